// Round 1
// 536.737 us; speedup vs baseline: 1.1366x; 1.1366x over previous
//
#include <hip/hip_runtime.h>

// CRF log-likelihood. B=256, L=1024, D=126, T=128. One block/batch, 512 thr.
// Forward recursion as fp32 matvec in probability domain. R4 retile: each
// thread computes 4 outputs (j) over 8 inputs (k) instead of 1x32, cutting
// E-operand LDS reads 4x (64 -> 16 ds_read_b128 per CU per step, the prior
// bottleneck). k-reduce via DPP row_ror ring over the 16-lane row. E is
// XOR-swizzled (f(k)=k^(4*(k>>5))) to keep the stride-32B reads 2-way.
// Rebase (exact power-of-2 rescale) only every 4th step. Raw
// lgkmcnt(0)+s_barrier per step so staged global loads (issued at sub==0,
// consumed at sub==8) are NOT drained by a compiler vmcnt(0) at barriers.

#define LOG2E   1.4426950408889634f
#define LN2     0.6931471805599453f

constexpr int Bc = 256, Lc = 1024, Dc = 126, Tc = 128;
constexpr int CH = 16, CHF = CH * Dc;       // 2016 floats per chunk
constexpr int NCH = Lc / CH;                // 64 chunks

#if __has_builtin(__builtin_amdgcn_exp2f)
#define FEXP2(x) __builtin_amdgcn_exp2f(x)
#else
#define FEXP2(x) exp2f(x)
#endif
#if __has_builtin(__builtin_amdgcn_logf)
#define FLOG2(x) __builtin_amdgcn_logf(x)
#else
#define FLOG2(x) log2f(x)
#endif

// DPP row_ror:N within 16-lane rows (ring-reduce: after ror 1,2,4,8 every
// lane holds the row total). Fallback: xor-butterfly is equivalent.
#if __has_builtin(__builtin_amdgcn_mov_dpp)
#define DPPF(x, ctrl) __int_as_float(__builtin_amdgcn_mov_dpp(__float_as_int(x), (ctrl), 0xF, 0xF, true))
#define ROR1(x) DPPF(x, 0x121)
#define ROR2(x) DPPF(x, 0x122)
#define ROR4(x) DPPF(x, 0x124)
#define ROR8(x) DPPF(x, 0x128)
#else
#define ROR1(x) __shfl_xor((x), 1, 64)
#define ROR2(x) __shfl_xor((x), 2, 64)
#define ROR4(x) __shfl_xor((x), 4, 64)
#define ROR8(x) __shfl_xor((x), 8, 64)
#endif

#define STEP_BARRIER() asm volatile("s_waitcnt lgkmcnt(0)\n\ts_barrier" ::: "memory")

__global__ __launch_bounds__(512, 1) void crf_fwd_kernel(
    const float* __restrict__ x,      // [B, L, D]
    const float* __restrict__ trans,  // [T, T] row-major
    const int*   __restrict__ x_len,  // [B]
    const int*   __restrict__ tag,    // [B, L]
    float*       __restrict__ out)    // [B]
{
    __shared__ __align__(16) float E[2][Tc];       // rebased exp(alpha), dbuf, XOR-swizzled
    __shared__ __align__(16) float Lbuf[2][CHF];   // staged logits, dbuf, linear
    __shared__ float red[12];                      // epilogue reductions

    const int b   = blockIdx.x;
    const int tid = threadIdx.x;
    const int w   = tid >> 6;            // wave 0..7
    const int l6  = tid & 63;
    const int o   = l6 & 15;             // k-octet: k in [8o, 8o+8)
    const int jg  = (w << 2) | (l6 >> 4);// j-group 0..31: j in [4jg, 4jg+4)
    const int len = x_len[b];            // block-uniform

    const float* xb = x   + (size_t)b * Lc * Dc;
    const int*   tb = tag + (size_t)b * Lc;

    // swizzled E float-index: f(k) = k ^ (4*(k>>5))  (2-way banks, bijective)
    const int sw   = 4 * (o >> 2);
    const int i0   = (o << 3) ^ sw;          // elements 8o..8o+3
    const int i1   = ((o << 3) + 4) ^ sw;    // elements 8o+4..8o+7
    const int jw   = 4 * jg + (o & 3);       // this lane's output j (o<4 writes)
    const int widx = jw ^ (4 * (jw >> 5));   // swizzled write index
    const int jr   = (jw < Dc) ? jw : 0;     // clamped logit index

    // ---- constant weights: treg[g][c] = exp(trans[4jg+g, 8o+c]) ----
    float treg[4][8];
#pragma unroll
    for (int g = 0; g < 4; ++g) {
        const float4* tp = reinterpret_cast<const float4*>(trans + (4*jg + g) * Tc + 8*o);
        float4 t0 = tp[0], t1 = tp[1];
        treg[g][0] = FEXP2(t0.x * LOG2E); treg[g][1] = FEXP2(t0.y * LOG2E);
        treg[g][2] = FEXP2(t0.z * LOG2E); treg[g][3] = FEXP2(t0.w * LOG2E);
        treg[g][4] = FEXP2(t1.x * LOG2E); treg[g][5] = FEXP2(t1.y * LOG2E);
        treg[g][6] = FEXP2(t1.z * LOG2E); treg[g][7] = FEXP2(t1.w * LOG2E);
    }

    // ---- preload chunk 0; init E = delta(START=126) ----
    {
        float4 q0 = make_float4(0.f, 0.f, 0.f, 0.f);
        if (tid < CHF / 4) q0 = *reinterpret_cast<const float4*>(xb + 4 * tid);
        if (tid < Tc) E[0][tid ^ (4 * (tid >> 5))] = (tid == Tc - 2) ? 1.0f : 0.0f;
        if (tid < CHF / 4) *reinterpret_cast<float4*>(&Lbuf[0][4 * tid]) = q0;
    }
    __syncthreads();

    float P    = (jw < Dc) ? FEXP2(Lbuf[0][jr] * LOG2E) : 0.0f;  // step-0 emission
    int   Mint = 0;                       // exact base-2 shift accumulator
    float4 stq = make_float4(0.f, 0.f, 0.f, 0.f);                // staging regs

    // ---- forward recursion: one raw barrier/step ----
    for (int l = 0; l < len; ++l) {
        const int p   = l & 1;
        const int sub = l & (CH - 1);
        const int cb  = (l >> 4) & 1;

        // staging (block-uniform): issue loads at sub==0 for chunk c+1;
        // ds_write them at sub==8 (compiler inserts the counted vmcnt wait
        // there; raw barriers don't drain vmcnt, so latency stays covered)
        if (sub == 0) {
            const int c1 = (l >> 4) + 1;
            if (c1 < NCH && tid < CHF / 4)
                stq = *reinterpret_cast<const float4*>(xb + (size_t)c1 * CHF + 4 * tid);
        } else if (sub == 8) {
            const int c1 = (l >> 4) + 1;
            if (c1 < NCH && tid < CHF / 4)
                *reinterpret_cast<float4*>(&Lbuf[cb ^ 1][4 * tid]) = stq;
        }

        // E operands: 2x ds_read_b128 (swizzled)
        const float* Ep = E[p];
        float4 ea  = *reinterpret_cast<const float4*>(Ep + i0);
        float4 eb4 = *reinterpret_cast<const float4*>(Ep + i1);

        // prefetch next-step logit early (off the post-reduce chain)
        const int ln = (l + 1 < len) ? (l + 1) : l;
        const float lv = Lbuf[(ln >> 4) & 1][(ln & (CH - 1)) * Dc + jr];

        // 4 outputs x 8 inputs = 32 FMA
        float a0 = treg[0][0] * ea.x, a1 = treg[1][0] * ea.x,
              a2 = treg[2][0] * ea.x, a3 = treg[3][0] * ea.x;
        a0 = fmaf(treg[0][1], ea.y, a0);  a1 = fmaf(treg[1][1], ea.y, a1);
        a2 = fmaf(treg[2][1], ea.y, a2);  a3 = fmaf(treg[3][1], ea.y, a3);
        a0 = fmaf(treg[0][2], ea.z, a0);  a1 = fmaf(treg[1][2], ea.z, a1);
        a2 = fmaf(treg[2][2], ea.z, a2);  a3 = fmaf(treg[3][2], ea.z, a3);
        a0 = fmaf(treg[0][3], ea.w, a0);  a1 = fmaf(treg[1][3], ea.w, a1);
        a2 = fmaf(treg[2][3], ea.w, a2);  a3 = fmaf(treg[3][3], ea.w, a3);
        a0 = fmaf(treg[0][4], eb4.x, a0); a1 = fmaf(treg[1][4], eb4.x, a1);
        a2 = fmaf(treg[2][4], eb4.x, a2); a3 = fmaf(treg[3][4], eb4.x, a3);
        a0 = fmaf(treg[0][5], eb4.y, a0); a1 = fmaf(treg[1][5], eb4.y, a1);
        a2 = fmaf(treg[2][5], eb4.y, a2); a3 = fmaf(treg[3][5], eb4.y, a3);
        a0 = fmaf(treg[0][6], eb4.z, a0); a1 = fmaf(treg[1][6], eb4.z, a1);
        a2 = fmaf(treg[2][6], eb4.z, a2); a3 = fmaf(treg[3][6], eb4.z, a3);
        a0 = fmaf(treg[0][7], eb4.w, a0); a1 = fmaf(treg[1][7], eb4.w, a1);
        a2 = fmaf(treg[2][7], eb4.w, a2); a3 = fmaf(treg[3][7], eb4.w, a3);

        // ring-reduce over the 16-lane row: every lane gets full sums
        a0 += ROR1(a0); a1 += ROR1(a1); a2 += ROR1(a2); a3 += ROR1(a3);
        a0 += ROR2(a0); a1 += ROR2(a1); a2 += ROR2(a2); a3 += ROR2(a3);
        a0 += ROR4(a0); a1 += ROR4(a1); a2 += ROR4(a2); a3 += ROR4(a3);
        a0 += ROR8(a0); a1 += ROR8(a1); a2 += ROR8(a2); a3 += ROR8(a3);

        // rebase every 4th step only (power-of-2 scale is numerically exact;
        // worst-case growth ~2^21/step keeps 4-step runs inside fp32 range)
        float R;
        if ((l & 3) == 3) {
            float mx = fmaxf(ea.z, eb4.z);           // samples k==2 mod 4
            mx = fmaxf(mx, ROR1(mx)); mx = fmaxf(mx, ROR2(mx));
            mx = fmaxf(mx, ROR4(mx)); mx = fmaxf(mx, ROR8(mx));
            int ebq = (__float_as_int(mx) >> 23) & 0xFF;
            R = __int_as_float((254 - ebq) << 23);   // 2^(127-ebq)
            Mint += ebq - 127;
        } else {
            R = 1.0f;
        }

        // lane o<4 owns j = 4jg+o: select its sum, apply emission + rebase
        float sel = a0;
        sel = (o == 1) ? a1 : sel;
        sel = (o == 2) ? a2 : sel;
        sel = (o == 3) ? a3 : sel;
        float eout = sel * P * R;
        if (o < 4) E[p ^ 1][widx] = eout;

        // next-step emission factor (lv already in flight)
        P = (jw < Dc) ? FEXP2(lv * LOG2E) : 0.0f;

        STEP_BARRIER();
    }
    const int pf = len & 1;              // final E buffer

    // ---- score: emission + pairwise transitions (cooperative over l) ----
    float acc = 0.f;
    for (int l = tid; l < len; l += 512) {
        int   tg = tb[l];
        float tr = (l == 0) ? trans[tg * Tc + (Tc - 2)]
                            : trans[tg * Tc + tb[l - 1]];
        acc += xb[(size_t)l * Dc + tg] + tr;
    }
#pragma unroll
    for (int off = 1; off < 64; off <<= 1)
        acc += __shfl_xor(acc, off, 64);
    if (l6 == 0) red[w] = acc;

    // ---- partition = ln2 * (Mint + log2(sum_k exp(t_stop_k) * E_k)) ----
    if (w == 0) {
        int k0i = l6, k1i = 64 + l6;
        float p0 = FEXP2(trans[(Tc-1) * Tc + k0i] * LOG2E) * E[pf][k0i ^ (4 * (k0i >> 5))];
        float p1 = FEXP2(trans[(Tc-1) * Tc + k1i] * LOG2E) * E[pf][k1i ^ (4 * (k1i >> 5))];
        float ps = p0 + p1;
#pragma unroll
        for (int off = 1; off < 64; off <<= 1)
            ps += __shfl_xor(ps, off, 64);
        if (l6 == 0) red[8] = LN2 * ((float)Mint + FLOG2(ps));
    }
    __syncthreads();

    if (tid == 0) {
        float sc = trans[(Tc-1) * Tc + tb[len - 1]];   // STOP transition
#pragma unroll
        for (int i = 0; i < 8; ++i) sc += red[i];
        out[b] = sc - red[8];
    }
}

extern "C" void kernel_launch(void* const* d_in, const int* in_sizes, int n_in,
                              void* d_out, int out_size, void* d_ws, size_t ws_size,
                              hipStream_t stream) {
    const float* x     = (const float*)d_in[0];
    const float* trans = (const float*)d_in[1];
    // d_in[2] = x_mask (redundant with x_len)
    const int*   x_len = (const int*)d_in[3];
    const int*   tag   = (const int*)d_in[4];
    float*       out   = (float*)d_out;

    crf_fwd_kernel<<<Bc, 512, 0, stream>>>(x, trans, x_len, tag, out);
}